// Round 1
// baseline (274.801 us; speedup 1.0000x reference)
//
#include <hip/hip_runtime.h>
#include <hip/hip_bf16.h>

// USR_EMB: out[b,h,:] = emb_usr[searchsorted(userlist, x[b,h]), :]
// EMB = 64 floats = 16 float4 = 256 B per row.
//
// Phase 1: 256 threads/block each binary-search one element's id -> LDS.
// Phase 2: block copies 256 rows; lane layout gives contiguous 1 KB/wave
//          stores and 256 B-segment gathered loads.

#define ELEMS_PER_BLOCK 256
#define V4_PER_ROW 16  // 64 floats / 4

__global__ __launch_bounds__(256) void usr_emb_gather(
    const int* __restrict__ x,
    const int* __restrict__ userlist, int n_user,
    const float* __restrict__ emb,
    float* __restrict__ out,
    int n_elem)
{
    __shared__ int s_id[ELEMS_PER_BLOCK];

    const int t    = threadIdx.x;
    const int base = blockIdx.x * ELEMS_PER_BLOCK;

    // ---- Phase 1: one lower_bound per thread ----
    {
        const int e = base + t;
        if (e < n_elem) {
            const int u = x[e];
            int lo = 0, hi = n_user;            // lower_bound over sorted userlist
            while (lo < hi) {
                const int mid = (lo + hi) >> 1;
                if (userlist[mid] < u) lo = mid + 1;
                else                   hi = mid;
            }
            s_id[t] = lo;
        }
    }
    __syncthreads();

    // ---- Phase 2: gather 256 rows as float4 ----
    const float4* __restrict__ emb4 = (const float4*)emb;
    float4*       __restrict__ out4 = (float4*)out;

    const int sub  = t & (V4_PER_ROW - 1);   // which float4 within the row
    const int eoff = t >> 4;                 // 0..15: element slot within stripe

#pragma unroll
    for (int iter = 0; iter < ELEMS_PER_BLOCK / 16; ++iter) {
        const int local_e = eoff + iter * 16;
        const int ge      = base + local_e;
        if (ge < n_elem) {
            const int id = s_id[local_e];
            out4[(size_t)ge * V4_PER_ROW + sub] = emb4[(size_t)id * V4_PER_ROW + sub];
        }
    }
}

extern "C" void kernel_launch(void* const* d_in, const int* in_sizes, int n_in,
                              void* d_out, int out_size, void* d_ws, size_t ws_size,
                              hipStream_t stream) {
    const int*   x        = (const int*)d_in[0];    // [BATCH*HIST] indices
    const int*   userlist = (const int*)d_in[1];    // [USR_SIZE+1] sorted ids
    const float* emb      = (const float*)d_in[2];  // [USR_SIZE+1, 64]
    float*       out      = (float*)d_out;          // [BATCH*HIST, 64]

    const int n_elem = in_sizes[0];                 // 819200
    const int n_user = in_sizes[1];                 // 100001

    const int blocks = (n_elem + ELEMS_PER_BLOCK - 1) / ELEMS_PER_BLOCK;  // 3200
    usr_emb_gather<<<blocks, 256, 0, stream>>>(x, userlist, n_user, emb, out, n_elem);
}

// Round 5
// 248.601 us; speedup vs baseline: 1.1054x; 1.1054x over previous
//
#include <hip/hip_runtime.h>
#include <hip/hip_bf16.h>

// USR_EMB: out[b,h,:] = emb_usr[searchsorted(userlist, x[b,h]), :]
// EMB = 64 floats = 16 float4 = 256 B per row.
//
// Phase 1 (per lane): interpolation probe — userlist is strictly increasing
//   and (in this dataset) a dense range, so guess = 1 + (u - userlist[1])
//   verifies in ONE load. Binary-search fallback keeps it correct for any
//   sorted unique userlist.
// Phase 2 (per wave, no LDS / no barrier): wave owns 64 elements; ids are
//   exchanged via __shfl. Lane layout: 16 lanes per row -> each wave-store
//   is 4 rows x 256 B = 1 KB contiguous; gathers are full 256 B segments.
// NOTE: reverted __builtin_nontemporal_store (R3/R4 container failures on
//   that source; plain stores were known-good in R1).

#define V4_PER_ROW 16  // 64 floats / 4

__global__ __launch_bounds__(256) void usr_emb_gather(
    const int* __restrict__ x,
    const int* __restrict__ userlist, int n_user,
    const float* __restrict__ emb,
    float* __restrict__ out,
    int n_elem)
{
    const int t      = threadIdx.x;
    const int lane   = t & 63;
    const int wave   = t >> 6;
    const int wbase  = blockIdx.x * 256 + wave * 64;   // first element of this wave

    // ---- Phase 1: one-probe lookup (fallback: binary search) ----
    int my_id = 0;
    {
        const int e = wbase + lane;
        if (e < n_elem) {
            const int u  = x[e];
            const int v1 = userlist[1];                // wave-uniform, L1-hit
            int g = 1 + (u - v1);
            bool hit = false;
            if (g >= 1 && g < n_user) {
                hit = (userlist[g] == u);              // strictly sorted => unique
            }
            if (!hit) {
                int lo = 0, hi = n_user;               // lower_bound fallback
                while (lo < hi) {
                    const int mid = (lo + hi) >> 1;
                    if (userlist[mid] < u) lo = mid + 1;
                    else                   hi = mid;
                }
                g = lo;
            }
            my_id = g;
        }
    }

    // ---- Phase 2: wave-local gather of 64 rows ----
    const float4* __restrict__ emb4 = (const float4*)emb;
    float4*       __restrict__ out4 = (float4*)out;

    const int sub   = lane & (V4_PER_ROW - 1);  // float4 index within row
    const int eslot = lane >> 4;                // 0..3

#pragma unroll
    for (int iter = 0; iter < 16; ++iter) {
        const int local = eslot + iter * 4;     // 0..63
        const int id    = __shfl(my_id, local); // id from owner lane
        const int ge    = wbase + local;
        if (ge < n_elem) {
            out4[(size_t)ge * V4_PER_ROW + sub] = emb4[(size_t)id * V4_PER_ROW + sub];
        }
    }
}

extern "C" void kernel_launch(void* const* d_in, const int* in_sizes, int n_in,
                              void* d_out, int out_size, void* d_ws, size_t ws_size,
                              hipStream_t stream) {
    const int*   x        = (const int*)d_in[0];    // [BATCH*HIST] indices
    const int*   userlist = (const int*)d_in[1];    // [USR_SIZE+1] sorted ids
    const float* emb      = (const float*)d_in[2];  // [USR_SIZE+1, 64]
    float*       out      = (float*)d_out;          // [BATCH*HIST, 64]

    const int n_elem = in_sizes[0];                 // 819200
    const int n_user = in_sizes[1];                 // 100001

    const int blocks = (n_elem + 255) / 256;        // 3200
    usr_emb_gather<<<blocks, 256, 0, stream>>>(x, userlist, n_user, emb, out, n_elem);
}